// Round 3
// baseline (126.064 us; speedup 1.0000x reference)
//
#include <hip/hip_runtime.h>

// Chamfer NN, single-pass pair loop (R1-verified math), stream-ordered.
// R2 post-mortem: fused cooperative kernel produced zeros == silent
// hipLaunchCooperativeKernel failure (return unchecked). Reverted to plain
// dispatches; this round removes the global-atomic merge instead:
//   path A (ws >= ~9.5MB): nn stores per-chunk partial mins with plain
//     coalesced stores (no memset, no global atomics, no 16.9MB L2
//     writeback thrash) -> wide 256-block reduce -> 1-block final.
//   path B (small ws): exact R1-proven atomic path (memset + atomicMin +
//     8-block out kernel), known-good 121us.
// Phase-1 math identical in both paths: d = |q|^2 + 2*(0.5|t|^2 - q.t),
// s2t min in registers, t2s min via skewed LDS ds_min_i32 (distances >= 0
// on this data, so float bits order as ints; clamped at 0 downstream).

constexpr int BATCH  = 8;
constexpr int NPTS   = 8192;           // N == M
constexpr int TCHUNK = 256;            // db points staged in LDS per block
constexpr int NSPLIT = NPTS / TCHUNK;  // 32 db chunks (grid.z)
constexpr int BLOCK  = 256;
constexpr int IPT    = 8;              // queries per thread
constexpr int QPB    = BLOCK * IPT;    // 2048 queries per block
constexpr int QBLKS  = NPTS / QPB;     // 4 query blocks

// path A workspace layout (floats)
constexpr size_t WS1_N = (size_t)NSPLIT * BATCH * NPTS;  // 8 MB s2t partials
constexpr size_t WS2_N = (size_t)QBLKS * BATCH * NPTS;   // 1 MB t2s partials
constexpr size_t WS3_N = (size_t)BATCH * 2 * 16;         // 1 KB block sums
constexpr size_t WS_A_BYTES = (WS1_N + WS2_N + WS3_N) * sizeof(float);

static __device__ __forceinline__ float fmin3(float a, float b, float c) {
    return fminf(fminf(a, b), c);   // fuses to v_min3_f32
}

template <bool STORE>
__global__ __launch_bounds__(BLOCK) void chamfer_nn(
    const float* __restrict__ src, const float* __restrict__ tgt,
    float* __restrict__ ws1,           // [NSPLIT][BATCH][NPTS]  (STORE)
    float* __restrict__ ws2,           // [QBLKS ][BATCH][NPTS]  (STORE)
    unsigned int* __restrict__ mins)   // [2][BATCH][NPTS]       (!STORE)
{
    __shared__ float4 sh[TCHUNK];   // (x, y, z, 0.5*|t|^2)
    __shared__ int    sht[TCHUNK];  // per-db-point t2s partial min (float bits)

    const int tid   = threadIdx.x;
    const int xblk  = blockIdx.x;
    const int b     = blockIdx.y;
    const int chunk = blockIdx.z;

    // --- stage db chunk (tgt) into LDS; init t2s partials (TCHUNK==BLOCK) ---
    {
        const float* dbase = tgt + ((size_t)b * NPTS + (size_t)chunk * TCHUNK) * 3;
        float x = dbase[3 * tid + 0];
        float y = dbase[3 * tid + 1];
        float z = dbase[3 * tid + 2];
        sh[tid]  = make_float4(x, y, z, 0.5f * fmaf(x, x, fmaf(y, y, z * z)));
        sht[tid] = 0x7f7f7f7f;  // ~3.39e38 as float bits
    }

    // --- load my IPT queries (negated coords) + |q|^2 ---
    float qnx[IPT], qny[IPT], qnz[IPT], qs[IPT], mn[IPT];
    const int q0 = xblk * QPB + tid;
    const float* pbase = src + (size_t)b * NPTS * 3;
#pragma unroll
    for (int k = 0; k < IPT; k++) {
        const float* p = pbase + (size_t)(q0 + k * BLOCK) * 3;
        float x = p[0], y = p[1], z = p[2];
        qnx[k] = -x; qny[k] = -y; qnz[k] = -z;
        qs[k]  = fmaf(x, x, fmaf(y, y, z * z));
        mn[k]  = 3.4e38f;
    }
    __syncthreads();

    // --- main loop: 2 db points x IPT queries per iter; skew j=(tid+s)&255
    //     keeps ds_read_b128 and ds_min_i32 conflict-free (distinct addrs) ---
#pragma unroll 2
    for (int s = 0; s < TCHUNK; s += 2) {
        const int j0 = (tid + s) & (TCHUNK - 1);
        const int j1 = (tid + s + 1) & (TCHUNK - 1);
        const float4 t0 = sh[j0];
        const float4 t1 = sh[j1];
        float r0 = 3.4e38f, r1 = 3.4e38f;
#pragma unroll
        for (int k = 0; k < IPT; k += 2) {
            float v00 = fmaf(qnx[k],   t0.x, fmaf(qny[k],   t0.y, fmaf(qnz[k],   t0.z, t0.w)));
            float v01 = fmaf(qnx[k],   t1.x, fmaf(qny[k],   t1.y, fmaf(qnz[k],   t1.z, t1.w)));
            float v10 = fmaf(qnx[k+1], t0.x, fmaf(qny[k+1], t0.y, fmaf(qnz[k+1], t0.z, t0.w)));
            float v11 = fmaf(qnx[k+1], t1.x, fmaf(qny[k+1], t1.y, fmaf(qnz[k+1], t1.z, t1.w)));
            float d00 = fmaf(2.0f, v00, qs[k]);
            float d01 = fmaf(2.0f, v01, qs[k]);
            float d10 = fmaf(2.0f, v10, qs[k+1]);
            float d11 = fmaf(2.0f, v11, qs[k+1]);
            mn[k]   = fmin3(mn[k],   d00, d01);   // s2t: min over db points
            mn[k+1] = fmin3(mn[k+1], d10, d11);
            r0 = fmin3(r0, d00, d10);             // t2s: min over my queries
            r1 = fmin3(r1, d01, d11);
        }
        atomicMin(&sht[j0], __float_as_int(r0));  // ds_min_i32, no-return
        atomicMin(&sht[j1], __float_as_int(r1));
    }

    if (STORE) {
        // --- plain coalesced partial stores; no init, no atomics ---
        float* w1 = ws1 + ((size_t)chunk * BATCH + b) * NPTS;
#pragma unroll
        for (int k = 0; k < IPT; k++)
            w1[q0 + k * BLOCK] = mn[k];
        __syncthreads();
        ws2[((size_t)xblk * BATCH + b) * NPTS + chunk * TCHUNK + tid] =
            __int_as_float(sht[tid]);
    } else {
        // --- R1-proven global atomicMin merge ---
        unsigned int* m0 = mins + (size_t)b * NPTS;
#pragma unroll
        for (int k = 0; k < IPT; k++) {
            float d = fmaxf(mn[k], 0.0f);
            atomicMin(&m0[q0 + k * BLOCK], __float_as_uint(d));
        }
        __syncthreads();
        unsigned int* m1 = mins + ((size_t)BATCH + b) * NPTS + (size_t)chunk * TCHUNK;
        float d = fmaxf(__int_as_float(sht[tid]), 0.0f);
        atomicMin(&m1[tid], __float_as_uint(d));
    }
}

// Path A reduce: grid (16 segs, 8 batches, 2 dirs) = 256 blocks, one CU each.
// dir 0: min over NSPLIT s2t partials; dir 1: min over QBLKS t2s partials.
// Coalesced loads, 32..64 independent loads per thread for MLP.
__global__ __launch_bounds__(BLOCK) void chamfer_reduce(
    const float* __restrict__ ws1, const float* __restrict__ ws2,
    float* __restrict__ ws3)
{
    const int seg = blockIdx.x;   // 16 segments of 512 elements
    const int b   = blockIdx.y;
    const int dir = blockIdx.z;
    const int tid = threadIdx.x;
    const int q0  = seg * 512 + tid;   // this thread: q0 and q0+256

    float m0 = 3.4e38f, m1 = 3.4e38f;
    if (dir == 0) {
#pragma unroll
        for (int c = 0; c < NSPLIT; c++) {
            const float* p = ws1 + ((size_t)c * BATCH + b) * NPTS;
            m0 = fminf(m0, p[q0]);
            m1 = fminf(m1, p[q0 + 256]);
        }
    } else {
#pragma unroll
        for (int x = 0; x < QBLKS; x++) {
            const float* p = ws2 + ((size_t)x * BATCH + b) * NPTS;
            m0 = fminf(m0, p[q0]);
            m1 = fminf(m1, p[q0 + 256]);
        }
    }
    float acc = fmaxf(m0, 0.0f) + fmaxf(m1, 0.0f);

    for (int off = 32; off > 0; off >>= 1) acc += __shfl_down(acc, off, 64);
    __shared__ float wsum[4];
    if ((tid & 63) == 0) wsum[tid >> 6] = acc;
    __syncthreads();
    if (tid == 0)
        ws3[((size_t)b * 2 + dir) * 16 + seg] = wsum[0] + wsum[1] + wsum[2] + wsum[3];
}

// Path A final: 1 block, 256 threads; 32 lanes per batch sum 32 slots.
__global__ __launch_bounds__(BLOCK) void chamfer_final(
    const float* __restrict__ ws3, float* __restrict__ out)
{
    const int b = threadIdx.x >> 5, i = threadIdx.x & 31;
    float s = ws3[b * 32 + i];
    for (int off = 16; off > 0; off >>= 1) s += __shfl_down(s, off, 32);
    if (i == 0) out[b] = s * (1.0f / (float)NPTS);
}

// Path B final (R1-proven): one block per batch sums atomic-merged mins.
__global__ __launch_bounds__(1024) void chamfer_out_kernel(
    const unsigned int* __restrict__ mins, float* __restrict__ out)
{
    const int b = blockIdx.x;
    float acc = 0.0f;
    for (int dir = 0; dir < 2; dir++) {
        const unsigned int* p = mins + ((size_t)dir * BATCH + b) * NPTS;
        for (int q = threadIdx.x; q < NPTS; q += 1024)
            acc += __uint_as_float(p[q]);
    }
    for (int off = 32; off > 0; off >>= 1) acc += __shfl_down(acc, off, 64);
    __shared__ float wsum[16];
    const int lane = threadIdx.x & 63;
    const int wid  = threadIdx.x >> 6;
    if (lane == 0) wsum[wid] = acc;
    __syncthreads();
    if (threadIdx.x < 64) {
        float s = (threadIdx.x < 16) ? wsum[threadIdx.x] : 0.0f;
        for (int off = 8; off > 0; off >>= 1) s += __shfl_down(s, off, 64);
        if (threadIdx.x == 0) out[b] = s * (1.0f / (float)NPTS);
    }
}

extern "C" void kernel_launch(void* const* d_in, const int* in_sizes, int n_in,
                              void* d_out, int out_size, void* d_ws, size_t ws_size,
                              hipStream_t stream) {
    const float* src = (const float*)d_in[0];  // [B, N, 3]
    const float* tgt = (const float*)d_in[1];  // [B, M, 3]
    float* out = (float*)d_out;                // [B]

    const dim3 grid(QBLKS, BATCH, NSPLIT);     // 4 x 8 x 32 = 1024 blocks

    if (ws_size >= WS_A_BYTES) {
        // ---- path A: plain partial stores, no memset, wide reduce ----
        float* ws1 = (float*)d_ws;
        float* ws2 = ws1 + WS1_N;
        float* ws3 = ws2 + WS2_N;
        chamfer_nn<true><<<grid, BLOCK, 0, stream>>>(src, tgt, ws1, ws2, nullptr);
        chamfer_reduce<<<dim3(16, BATCH, 2), BLOCK, 0, stream>>>(ws1, ws2, ws3);
        chamfer_final<<<1, BLOCK, 0, stream>>>(ws3, out);
    } else {
        // ---- path B: R1-proven atomic path ----
        unsigned int* mins = (unsigned int*)d_ws;  // [2][B][NPTS] = 512 KB
        const size_t min_bytes = (size_t)2 * BATCH * NPTS * sizeof(unsigned int);
        hipMemsetAsync(d_ws, 0x7f, min_bytes, stream);
        chamfer_nn<false><<<grid, BLOCK, 0, stream>>>(src, tgt, nullptr, nullptr, mins);
        chamfer_out_kernel<<<BATCH, 1024, 0, stream>>>(mins, out);
    }
}

// Round 4
// 124.015 us; speedup vs baseline: 1.0165x; 1.0165x over previous
//
#include <hip/hip_runtime.h>

// Chamfer NN, single-pass pair loop, stream-ordered dispatches.
// R3 post-mortem: atomics were NOT the cost (removal gained ~0); nn is
// latency/occupancy-bound: grid supplied only 16 waves/CU (1024 blocks) and
// OccupancyPercent pinned at ~29%, while VALU issue model = ~37us vs 72.6
// measured. R4: 2048 blocks (TCHUNK=128, IPT=8, QBLKS=4) -> 8 blocks/CU,
// 32 waves/CU; __launch_bounds__(256,8) forces VGPR<=64 (R3 compiled at 40).
// DS traffic: 128 reads + 128 ds_min per thread; measured incremental DS
// cost ~3.3cyc/op (R1->R3 delta) -> hidden under VALU at 8 waves/SIMD.
// Merge: plain coalesced partial stores (no memset, no global atomics);
// ws1 = 64 chunk-copies of s2t mins (16MB), ws2 = 4 copies t2s (1MB).
// Fallback (small ws): R1-proven global-atomicMin path, known ~121us.

constexpr int BATCH  = 8;
constexpr int NPTS   = 8192;           // N == M
constexpr int TCHUNK = 128;            // db points staged in LDS per block
constexpr int NSPLIT = NPTS / TCHUNK;  // 64 db chunks (grid.z)
constexpr int BLOCK  = 256;
constexpr int IPT    = 8;              // queries per thread
constexpr int QPB    = BLOCK * IPT;    // 2048 queries per block
constexpr int QBLKS  = NPTS / QPB;     // 4 query blocks

// path A workspace layout (floats)
constexpr size_t WS1_N = (size_t)NSPLIT * BATCH * NPTS;  // 16 MB s2t partials
constexpr size_t WS2_N = (size_t)QBLKS * BATCH * NPTS;   // 1 MB t2s partials
constexpr size_t WS3_N = (size_t)BATCH * 2 * 8;          // 512 B block sums
constexpr size_t WS_A_BYTES = (WS1_N + WS2_N + WS3_N) * sizeof(float);

static __device__ __forceinline__ float fmin3(float a, float b, float c) {
    return fminf(fminf(a, b), c);   // fuses to v_min3_f32
}

template <bool STORE>
__global__ __launch_bounds__(BLOCK, 8) void chamfer_nn(
    const float* __restrict__ src, const float* __restrict__ tgt,
    float* __restrict__ ws1,           // [NSPLIT][BATCH][NPTS]  (STORE)
    float* __restrict__ ws2,           // [QBLKS ][BATCH][NPTS]  (STORE)
    unsigned int* __restrict__ mins)   // [2][BATCH][NPTS]       (!STORE)
{
    __shared__ float4 sh[TCHUNK];   // (x, y, z, 0.5*|t|^2)
    __shared__ int    sht[TCHUNK];  // per-db-point t2s partial min (float bits)

    const int tid   = threadIdx.x;
    const int xblk  = blockIdx.x;
    const int b     = blockIdx.y;
    const int chunk = blockIdx.z;

    // --- stage db chunk (tgt) into LDS; init t2s partials (TCHUNK<BLOCK) ---
    if (tid < TCHUNK) {
        const float* dbase = tgt + ((size_t)b * NPTS + (size_t)chunk * TCHUNK) * 3;
        float x = dbase[3 * tid + 0];
        float y = dbase[3 * tid + 1];
        float z = dbase[3 * tid + 2];
        sh[tid]  = make_float4(x, y, z, 0.5f * fmaf(x, x, fmaf(y, y, z * z)));
        sht[tid] = 0x7f7f7f7f;  // ~3.39e38 as float bits
    }

    // --- load my IPT queries (negated coords) + |q|^2 ---
    float qnx[IPT], qny[IPT], qnz[IPT], qs[IPT], mn[IPT];
    const int q0 = xblk * QPB + tid;
    const float* pbase = src + (size_t)b * NPTS * 3;
#pragma unroll
    for (int k = 0; k < IPT; k++) {
        const float* p = pbase + (size_t)(q0 + k * BLOCK) * 3;
        float x = p[0], y = p[1], z = p[2];
        qnx[k] = -x; qny[k] = -y; qnz[k] = -z;
        qs[k]  = fmaf(x, x, fmaf(y, y, z * z));
        mn[k]  = 3.4e38f;
    }
    __syncthreads();

    // --- main loop: 2 db points x IPT queries per iter; skew j=(tid+s)&127
    //     gives 64 distinct LDS addrs per wave for reads and ds_min ---
#pragma unroll 2
    for (int s = 0; s < TCHUNK; s += 2) {
        const int j0 = (tid + s) & (TCHUNK - 1);
        const int j1 = (tid + s + 1) & (TCHUNK - 1);
        const float4 t0 = sh[j0];
        const float4 t1 = sh[j1];
        float r0 = 3.4e38f, r1 = 3.4e38f;
#pragma unroll
        for (int k = 0; k < IPT; k += 2) {
            float v00 = fmaf(qnx[k],   t0.x, fmaf(qny[k],   t0.y, fmaf(qnz[k],   t0.z, t0.w)));
            float v01 = fmaf(qnx[k],   t1.x, fmaf(qny[k],   t1.y, fmaf(qnz[k],   t1.z, t1.w)));
            float v10 = fmaf(qnx[k+1], t0.x, fmaf(qny[k+1], t0.y, fmaf(qnz[k+1], t0.z, t0.w)));
            float v11 = fmaf(qnx[k+1], t1.x, fmaf(qny[k+1], t1.y, fmaf(qnz[k+1], t1.z, t1.w)));
            float d00 = fmaf(2.0f, v00, qs[k]);
            float d01 = fmaf(2.0f, v01, qs[k]);
            float d10 = fmaf(2.0f, v10, qs[k+1]);
            float d11 = fmaf(2.0f, v11, qs[k+1]);
            mn[k]   = fmin3(mn[k],   d00, d01);   // s2t: min over db points
            mn[k+1] = fmin3(mn[k+1], d10, d11);
            r0 = fmin3(r0, d00, d10);             // t2s: min over my queries
            r1 = fmin3(r1, d01, d11);
        }
        atomicMin(&sht[j0], __float_as_int(r0));  // ds_min_i32, no-return
        atomicMin(&sht[j1], __float_as_int(r1));
    }

    if (STORE) {
        // --- plain coalesced partial stores; no init, no atomics ---
        float* w1 = ws1 + ((size_t)chunk * BATCH + b) * NPTS;
#pragma unroll
        for (int k = 0; k < IPT; k++)
            w1[q0 + k * BLOCK] = mn[k];
        __syncthreads();
        if (tid < TCHUNK)
            ws2[((size_t)xblk * BATCH + b) * NPTS + chunk * TCHUNK + tid] =
                __int_as_float(sht[tid]);
    } else {
        // --- R1-proven global atomicMin merge ---
        unsigned int* m0 = mins + (size_t)b * NPTS;
#pragma unroll
        for (int k = 0; k < IPT; k++) {
            float d = fmaxf(mn[k], 0.0f);
            atomicMin(&m0[q0 + k * BLOCK], __float_as_uint(d));
        }
        __syncthreads();
        if (tid < TCHUNK) {
            unsigned int* m1 = mins + ((size_t)BATCH + b) * NPTS + (size_t)chunk * TCHUNK;
            float d = fmaxf(__int_as_float(sht[tid]), 0.0f);
            atomicMin(&m1[tid], __float_as_uint(d));
        }
    }
}

// Path A reduce: grid (8 segs, 8 batches, 2 dirs) = 128 blocks.
// Each block: 1024 queries as 256 float4 columns, one per thread.
// dir 0: min over NSPLIT chunk-copies (16MB total, L3-resident);
// dir 1: min over QBLKS copies (1MB). All loads dwordx4, coalesced.
__global__ __launch_bounds__(BLOCK) void chamfer_reduce(
    const float* __restrict__ ws1, const float* __restrict__ ws2,
    float* __restrict__ ws3)
{
    const int seg = blockIdx.x;            // 8 segments of 1024 queries
    const int b   = blockIdx.y;
    const int dir = blockIdx.z;
    const int col = seg * 256 + threadIdx.x;   // float4 column in [0, 2048)

    float4 m = make_float4(3.4e38f, 3.4e38f, 3.4e38f, 3.4e38f);
    if (dir == 0) {
#pragma unroll 4
        for (int c = 0; c < NSPLIT; c++) {
            const float4* p = (const float4*)(ws1 + ((size_t)c * BATCH + b) * NPTS);
            float4 v = p[col];
            m.x = fminf(m.x, v.x); m.y = fminf(m.y, v.y);
            m.z = fminf(m.z, v.z); m.w = fminf(m.w, v.w);
        }
    } else {
#pragma unroll
        for (int x = 0; x < QBLKS; x++) {
            const float4* p = (const float4*)(ws2 + ((size_t)x * BATCH + b) * NPTS);
            float4 v = p[col];
            m.x = fminf(m.x, v.x); m.y = fminf(m.y, v.y);
            m.z = fminf(m.z, v.z); m.w = fminf(m.w, v.w);
        }
    }
    float acc = fmaxf(m.x, 0.0f) + fmaxf(m.y, 0.0f) +
                fmaxf(m.z, 0.0f) + fmaxf(m.w, 0.0f);

    for (int off = 32; off > 0; off >>= 1) acc += __shfl_down(acc, off, 64);
    __shared__ float wsum[4];
    if ((threadIdx.x & 63) == 0) wsum[threadIdx.x >> 6] = acc;
    __syncthreads();
    if (threadIdx.x == 0)
        ws3[((size_t)b * 2 + dir) * 8 + seg] = wsum[0] + wsum[1] + wsum[2] + wsum[3];
}

// Path A final: 1 block, 256 threads; 32 lanes per batch sum 16 slots.
__global__ __launch_bounds__(BLOCK) void chamfer_final(
    const float* __restrict__ ws3, float* __restrict__ out)
{
    const int b = threadIdx.x >> 5, i = threadIdx.x & 31;
    float s = (i < 16) ? ws3[b * 16 + i] : 0.0f;
    for (int off = 16; off > 0; off >>= 1) s += __shfl_down(s, off, 32);
    if (i == 0) out[b] = s * (1.0f / (float)NPTS);
}

// Path B final (R1-proven): one block per batch sums atomic-merged mins.
__global__ __launch_bounds__(1024) void chamfer_out_kernel(
    const unsigned int* __restrict__ mins, float* __restrict__ out)
{
    const int b = blockIdx.x;
    float acc = 0.0f;
    for (int dir = 0; dir < 2; dir++) {
        const unsigned int* p = mins + ((size_t)dir * BATCH + b) * NPTS;
        for (int q = threadIdx.x; q < NPTS; q += 1024)
            acc += __uint_as_float(p[q]);
    }
    for (int off = 32; off > 0; off >>= 1) acc += __shfl_down(acc, off, 64);
    __shared__ float wsum[16];
    const int lane = threadIdx.x & 63;
    const int wid  = threadIdx.x >> 6;
    if (lane == 0) wsum[wid] = acc;
    __syncthreads();
    if (threadIdx.x < 64) {
        float s = (threadIdx.x < 16) ? wsum[threadIdx.x] : 0.0f;
        for (int off = 8; off > 0; off >>= 1) s += __shfl_down(s, off, 64);
        if (threadIdx.x == 0) out[b] = s * (1.0f / (float)NPTS);
    }
}

extern "C" void kernel_launch(void* const* d_in, const int* in_sizes, int n_in,
                              void* d_out, int out_size, void* d_ws, size_t ws_size,
                              hipStream_t stream) {
    const float* src = (const float*)d_in[0];  // [B, N, 3]
    const float* tgt = (const float*)d_in[1];  // [B, M, 3]
    float* out = (float*)d_out;                // [B]

    const dim3 grid(QBLKS, BATCH, NSPLIT);     // 4 x 8 x 64 = 2048 blocks

    if (ws_size >= WS_A_BYTES) {
        // ---- path A: plain partial stores, no memset, wide reduce ----
        float* ws1 = (float*)d_ws;
        float* ws2 = ws1 + WS1_N;
        float* ws3 = ws2 + WS2_N;
        chamfer_nn<true><<<grid, BLOCK, 0, stream>>>(src, tgt, ws1, ws2, nullptr);
        chamfer_reduce<<<dim3(8, BATCH, 2), BLOCK, 0, stream>>>(ws1, ws2, ws3);
        chamfer_final<<<1, BLOCK, 0, stream>>>(ws3, out);
    } else {
        // ---- path B: R1-proven atomic path ----
        unsigned int* mins = (unsigned int*)d_ws;  // [2][B][NPTS] = 512 KB
        const size_t min_bytes = (size_t)2 * BATCH * NPTS * sizeof(unsigned int);
        hipMemsetAsync(d_ws, 0x7f, min_bytes, stream);
        chamfer_nn<false><<<grid, BLOCK, 0, stream>>>(src, tgt, nullptr, nullptr, mins);
        chamfer_out_kernel<<<BATCH, 1024, 0, stream>>>(mins, out);
    }
}

// Round 5
// 118.735 us; speedup vs baseline: 1.0617x; 1.0445x over previous
//
#include <hip/hip_runtime.h>

// Chamfer via MFMA half-distance matrix. R4 post-mortem: scalar path is
// VALU-execution-bound at ~19.6 cyc/pair-wave (sustained VOP3 ~3-3.7
// cyc/inst, cf m07's 103TF); occupancy 29->48% changed nothing. Fix: compute
// h = 0.5|q|^2 + 0.5|t|^2 - q.t  (= d/2, >= 0) on the MATRIX pipe with
// bf16 hi/lo splitting packed into K=16 of v_mfma_f32_32x32x16_bf16:
//   A(q) k-slots: [xh xh xl | yh yh yl | zh zh | zl hqh hql 1 1 0 0 0]
//   B(t) k-slots: [nxh nxl nxh|nyh nyl nyh|nzh nzl|nzh 1 1 hth htl 0 0 0]
//   (n* = negated t coords) -> sum = -q.t (3-term split products) + hq + ht.
// Dropped lo*lo terms ~1e-5; output is a mean of mins, threshold 9.5e-4.
// Chamfer means are invariant to consistent row/col permutations inside
// tiles, so only k-slot pairing consistency between A and B matters.
// C layout (HW-verified m74/m101): col=lane&31, row=(reg&3)+8*(reg>>2)
// +4*(lane>>5). Row-mins accumulate in regs across tiles (rmn[16]);
// col-mins: min3-tree over 16 regs + shfl_xor(32) + ds_min.

typedef float f32x16 __attribute__((ext_vector_type(16)));
typedef short bf16x8 __attribute__((ext_vector_type(8)));

constexpr int BATCH  = 8;
constexpr int NPTS   = 8192;
constexpr int BLOCK  = 256;            // 4 waves
constexpr int QTILE  = 128;            // queries per block (32 per wave)
constexpr int QB     = NPTS / QTILE;   // 64 query blocks
constexpr int DSPLIT = 2;              // db split (grid.z)
constexpr int DBR    = NPTS / DSPLIT;  // 4096 db points per block
constexpr int CH     = 256;            // db points per LDS chunk (== BLOCK)
constexpr int NCH    = DBR / CH;       // 16 chunks

// workspace (floats): ws1 = s2t partials [DSPLIT][B][NPTS] (512 KB),
//                     ws2 = t2s partials [QB][B][NPTS]     (16 MB)
constexpr size_t WS1_N = (size_t)DSPLIT * BATCH * NPTS;
constexpr size_t WS2_N = (size_t)QB * BATCH * NPTS;

static __device__ __forceinline__ float fmin3(float a, float b, float c) {
    return fminf(fminf(a, b), c);   // v_min3_f32
}
static __device__ __forceinline__ unsigned short bf16h(float f) {
    unsigned int u = __float_as_uint(f);
    u += 0x7fffu + ((u >> 16) & 1u);           // RNE
    return (unsigned short)(u >> 16);
}
static __device__ __forceinline__ float bf16tof(unsigned short h) {
    return __uint_as_float(((unsigned int)h) << 16);
}
static __device__ __forceinline__ unsigned int pack2(unsigned short a, unsigned short b) {
    return (unsigned int)a | ((unsigned int)b << 16);
}
static __device__ __forceinline__ float tree16(const f32x16& a) {
    float m = fmin3(a[0], a[1], a[2]);
    m = fmin3(m, a[3], a[4]);   m = fmin3(m, a[5], a[6]);
    m = fmin3(m, a[7], a[8]);   m = fmin3(m, a[9], a[10]);
    m = fmin3(m, a[11], a[12]); m = fmin3(m, a[13], a[14]);
    return fminf(m, a[15]);
}

__global__ __launch_bounds__(BLOCK) void chamfer_nn(
    const float* __restrict__ src, const float* __restrict__ tgt,
    float* __restrict__ ws1, float* __restrict__ ws2, float* __restrict__ out)
{
    __shared__ uint4 Bfr[2][CH];    // staged B fragments: [k-half][point] 16B
    __shared__ int   sht[CH];       // per-db-point col-min (float bits)
    __shared__ int   srow[QTILE];   // per-query row-min (float bits)

    const int tid  = threadIdx.x;
    const int lane = tid & 63;
    const int w    = tid >> 6;      // wave 0..3
    const int half = lane >> 5;
    const int l31  = lane & 31;
    const int qb   = blockIdx.x;
    const int b    = blockIdx.y;
    const int ds   = blockIdx.z;

    // zero the output once (reduce kernel atomicAdds into it; stream order
    // guarantees nn completes first).
    if (qb == 0 && b == 0 && ds == 0 && tid < BATCH) out[tid] = 0.0f;
    if (tid < QTILE) srow[tid] = 0x7f7f7f7f;

    // ---- build my wave's A-fragment (32 queries x K=16) in registers ----
    const unsigned short one = bf16h(1.0f);
    bf16x8 afrag;
    {
        const int q = qb * QTILE + w * 32 + l31;
        const float* qp = src + ((size_t)b * NPTS + q) * 3;
        float qx = qp[0], qy = qp[1], qz = qp[2];
        float hq = 0.5f * fmaf(qx, qx, fmaf(qy, qy, qz * qz));
        unsigned short xh = bf16h(qx), xl = bf16h(qx - bf16tof(xh));
        unsigned short yh = bf16h(qy), yl = bf16h(qy - bf16tof(yh));
        unsigned short zh = bf16h(qz), zl = bf16h(qz - bf16tof(zh));
        unsigned short qh = bf16h(hq), ql = bf16h(hq - bf16tof(qh));
        if (half == 0) {
            afrag[0] = (short)xh; afrag[1] = (short)xh; afrag[2] = (short)xl;
            afrag[3] = (short)yh; afrag[4] = (short)yh; afrag[5] = (short)yl;
            afrag[6] = (short)zh; afrag[7] = (short)zh;
        } else {
            afrag[0] = (short)zl; afrag[1] = (short)qh; afrag[2] = (short)ql;
            afrag[3] = (short)one; afrag[4] = (short)one;
            afrag[5] = 0; afrag[6] = 0; afrag[7] = 0;
        }
    }

    float rmn[16];
#pragma unroll
    for (int r = 0; r < 16; r++) rmn[r] = 3.4e38f;
    const f32x16 zz = {};   // zero accumulator input

    // ---- db loop: prefetch -> convert/stage -> 8 MFMA tiles per chunk ----
    const float* dbase = tgt + ((size_t)b * NPTS + ds * DBR) * 3;
    float px, py, pz;
    { const float* tp = dbase + (size_t)tid * 3; px = tp[0]; py = tp[1]; pz = tp[2]; }

    float* w2 = ws2 + ((size_t)qb * BATCH + b) * NPTS + (size_t)ds * DBR;

    for (int c = 0; c < NCH; ++c) {
        // convert my staged point (VALU only, before barrier)
        float nx = -px, ny = -py, nz = -pz;
        float ht = 0.5f * fmaf(px, px, fmaf(py, py, pz * pz));
        unsigned short nxh = bf16h(nx), nxl = bf16h(nx - bf16tof(nxh));
        unsigned short nyh = bf16h(ny), nyl = bf16h(ny - bf16tof(nyh));
        unsigned short nzh = bf16h(nz), nzl = bf16h(nz - bf16tof(nzh));
        unsigned short hh = bf16h(ht),  hl = bf16h(ht - bf16tof(hh));
        uint4 p0 = make_uint4(pack2(nxh, nxl), pack2(nxh, nyh),
                              pack2(nyl, nyh), pack2(nzh, nzl));
        uint4 p1 = make_uint4(pack2(nzh, one), pack2(one, hh),
                              pack2(hl, 0), 0u);

        __syncthreads();                       // prev chunk's reads/ds_min done
        if (c > 0) w2[(c - 1) * CH + tid] = __int_as_float(sht[tid]);
        sht[tid] = 0x7f7f7f7f;
        Bfr[0][tid] = p0;
        Bfr[1][tid] = p1;
        __syncthreads();                       // staging visible

        if (c + 1 < NCH) {                     // prefetch next chunk (hidden)
            const float* tp = dbase + ((size_t)(c + 1) * CH + tid) * 3;
            px = tp[0]; py = tp[1]; pz = tp[2];
        }

#pragma unroll
        for (int tp2 = 0; tp2 < CH / 64; ++tp2) {   // 4 tile-pairs
            const int t0 = tp2 * 2, t1 = tp2 * 2 + 1;
            bf16x8 b0 = *reinterpret_cast<const bf16x8*>(&Bfr[half][t0 * 32 + l31]);
            bf16x8 b1 = *reinterpret_cast<const bf16x8*>(&Bfr[half][t1 * 32 + l31]);
            f32x16 acc0 = __builtin_amdgcn_mfma_f32_32x32x16_bf16(afrag, b0, zz, 0, 0, 0);
            f32x16 acc1 = __builtin_amdgcn_mfma_f32_32x32x16_bf16(afrag, b1, zz, 0, 0, 0);
#pragma unroll
            for (int r = 0; r < 16; r++) rmn[r] = fmin3(rmn[r], acc0[r], acc1[r]);
            float c0 = tree16(acc0);
            float c1 = tree16(acc1);
            c0 = fminf(c0, __shfl_xor(c0, 32, 64));
            c1 = fminf(c1, __shfl_xor(c1, 32, 64));
            atomicMin(&sht[t0 * 32 + l31], __float_as_int(c0));
            atomicMin(&sht[t1 * 32 + l31], __float_as_int(c1));
        }
    }

    __syncthreads();
    w2[(NCH - 1) * CH + tid] = __int_as_float(sht[tid]);

    // ---- s2t finalize: fold rmn into per-query LDS slots, store ws1 ----
#pragma unroll
    for (int r = 0; r < 16; r++) {
        const int row = (r & 3) + 8 * (r >> 2) + 4 * half;
        atomicMin(&srow[w * 32 + row], __float_as_int(rmn[r]));
    }
    __syncthreads();
    if (tid < QTILE)
        ws1[((size_t)ds * BATCH + b) * NPTS + (size_t)qb * QTILE + tid] =
            __int_as_float(srow[tid]);
}

// Reduce + final (fused): min over partial copies, clamp, d = 2h, block-sum,
// atomicAdd into out (zeroed by nn). grid (8 segs, BATCH, 2 dirs).
__global__ __launch_bounds__(BLOCK) void chamfer_reduce(
    const float* __restrict__ ws1, const float* __restrict__ ws2,
    float* __restrict__ out)
{
    const int seg = blockIdx.x;
    const int b   = blockIdx.y;
    const int dir = blockIdx.z;
    const int col = seg * 256 + threadIdx.x;   // float4 column in [0, 2048)

    float4 m = make_float4(3.4e38f, 3.4e38f, 3.4e38f, 3.4e38f);
    if (dir == 0) {
#pragma unroll
        for (int c = 0; c < DSPLIT; c++) {
            const float4* p = (const float4*)(ws1 + ((size_t)c * BATCH + b) * NPTS);
            float4 v = p[col];
            m.x = fminf(m.x, v.x); m.y = fminf(m.y, v.y);
            m.z = fminf(m.z, v.z); m.w = fminf(m.w, v.w);
        }
    } else {
#pragma unroll 8
        for (int q = 0; q < QB; q++) {
            const float4* p = (const float4*)(ws2 + ((size_t)q * BATCH + b) * NPTS);
            float4 v = p[col];
            m.x = fminf(m.x, v.x); m.y = fminf(m.y, v.y);
            m.z = fminf(m.z, v.z); m.w = fminf(m.w, v.w);
        }
    }
    // stored values are half-distances: d = 2*max(h,0)
    float acc = fmaxf(m.x, 0.0f) + fmaxf(m.y, 0.0f) +
                fmaxf(m.z, 0.0f) + fmaxf(m.w, 0.0f);

    for (int off = 32; off > 0; off >>= 1) acc += __shfl_down(acc, off, 64);
    __shared__ float wsum[4];
    if ((threadIdx.x & 63) == 0) wsum[threadIdx.x >> 6] = acc;
    __syncthreads();
    if (threadIdx.x == 0) {
        float s = (wsum[0] + wsum[1] + wsum[2] + wsum[3]) * (2.0f / (float)NPTS);
        atomicAdd(&out[b], s);
    }
}

extern "C" void kernel_launch(void* const* d_in, const int* in_sizes, int n_in,
                              void* d_out, int out_size, void* d_ws, size_t ws_size,
                              hipStream_t stream) {
    const float* src = (const float*)d_in[0];  // [B, N, 3]
    const float* tgt = (const float*)d_in[1];  // [B, M, 3]
    float* out = (float*)d_out;                // [B]

    // ws requirement 17.3 MB; R4's path A (17.83 MB) ran on this harness.
    float* ws1 = (float*)d_ws;
    float* ws2 = ws1 + WS1_N;

    chamfer_nn<<<dim3(QB, BATCH, DSPLIT), BLOCK, 0, stream>>>(src, tgt, ws1, ws2, out);
    chamfer_reduce<<<dim3(8, BATCH, 2), BLOCK, 0, stream>>>(ws1, ws2, out);
}

// Round 6
// 106.675 us; speedup vs baseline: 1.1818x; 1.1131x over previous
//
#include <hip/hip_runtime.h>

// Chamfer via MFMA half-distance matrix, v2 (R5 verified the numerics:
// absmax 0.0 with the bf16 hi/lo split; this round removes the overhead
// around the MFMA).
// R5 post-mortem: MfmaUtil 10%, VALUBusy 55%, 4M LDS conflicts. Costs:
//  (1) per-block re-conversion of db points to split-bf16 (64x redundant)
//  (2) s2t tail via 32-way SAME-ADDRESS LDS atomics (row indep of lane)
//  (3) 4 waves re-reading identical B tiles + 2 bpermute per tile-pair.
// R6: prep kernel precomputes B-fragments once (+ inits t2s mins + zeroes
// out); nn uses 64 queries/wave (2 A-frags -> 4 MFMAs per B-read, halving
// broadcast DS reads per pair); s2t tail folds 32->8 cols with 2 shfl_xor
// and stores 8 partials/query coalesced (ws1 4MB); t2s via R3-proven-free
// global atomicMin. 3 dispatches, ws ~6.25MB (17.8MB proven available).
//
// Math (R5-verified, absmax 0.0): h = 0.5|q|^2 + 0.5|t|^2 - q.t = d/2 via
// K=16 of v_mfma_f32_32x32x16_bf16:
//   A(q): half0 [xh xh xl yh yh yl zh zh]  half1 [zl qh ql 1 1 0 0 0]
//   B(t): half0 [nxh nxl nxh nyh nyl nyh nzh nzl] half1 [nzh 1 1 hh hl 0 0 0]
// C layout (m74/m101): col=lane&31, row=(reg&3)+8*(reg>>2)+4*(lane>>5).

typedef float f32x16 __attribute__((ext_vector_type(16)));
typedef short bf16x8 __attribute__((ext_vector_type(8)));

constexpr int BATCH  = 8;
constexpr int NPTS   = 8192;
constexpr int BLOCK  = 256;            // 4 waves
constexpr int QTILE  = 256;            // queries per block (64 per wave)
constexpr int QB     = NPTS / QTILE;   // 32 query blocks
constexpr int DSPLIT = 2;
constexpr int DBR    = NPTS / DSPLIT;  // 4096 db points per block
constexpr int CH     = 256;            // db points per LDS chunk
constexpr int NCH    = DBR / CH;       // 16 chunks

// workspace carve: fragB [B][NPTS][2] uint4 (2MB) | ws1 s2t partials
// [DSPLIT][B][NPTS][8] float (4MB) | tmins [B][NPTS] uint (256KB)
constexpr size_t FRAGB_N = (size_t)BATCH * NPTS * 2;       // uint4s
constexpr size_t WS1_N   = (size_t)DSPLIT * BATCH * NPTS * 8;  // floats
constexpr size_t TM_N    = (size_t)BATCH * NPTS;           // uints

static __device__ __forceinline__ float fmin3(float a, float b, float c) {
    return fminf(fminf(a, b), c);   // v_min3_f32
}
static __device__ __forceinline__ unsigned short bf16h(float f) {
    unsigned int u = __float_as_uint(f);
    u += 0x7fffu + ((u >> 16) & 1u);           // RNE
    return (unsigned short)(u >> 16);
}
static __device__ __forceinline__ float bf16tof(unsigned short h) {
    return __uint_as_float(((unsigned int)h) << 16);
}
static __device__ __forceinline__ unsigned int pack2(unsigned short a, unsigned short b) {
    return (unsigned int)a | ((unsigned int)b << 16);
}
static __device__ __forceinline__ float tree16(const f32x16& a) {
    float m = fmin3(a[0], a[1], a[2]);
    m = fmin3(m, a[3], a[4]);   m = fmin3(m, a[5], a[6]);
    m = fmin3(m, a[7], a[8]);   m = fmin3(m, a[9], a[10]);
    m = fmin3(m, a[11], a[12]); m = fmin3(m, a[13], a[14]);
    return fminf(m, a[15]);
}

// ---- prep: tgt -> split-bf16 B-fragments; init tmins; zero out ----
__global__ __launch_bounds__(BLOCK) void chamfer_prep(
    const float* __restrict__ tgt, uint4* __restrict__ fragB,
    unsigned int* __restrict__ tmins, float* __restrict__ out)
{
    const int i = blockIdx.x * BLOCK + threadIdx.x;   // [0, B*NPTS)
    const float* tp = tgt + (size_t)i * 3;
    float px = tp[0], py = tp[1], pz = tp[2];
    float nx = -px, ny = -py, nz = -pz;
    float ht = 0.5f * fmaf(px, px, fmaf(py, py, pz * pz));
    const unsigned short one = bf16h(1.0f);
    unsigned short nxh = bf16h(nx), nxl = bf16h(nx - bf16tof(nxh));
    unsigned short nyh = bf16h(ny), nyl = bf16h(ny - bf16tof(nyh));
    unsigned short nzh = bf16h(nz), nzl = bf16h(nz - bf16tof(nzh));
    unsigned short hh = bf16h(ht),  hl = bf16h(ht - bf16tof(hh));
    fragB[2 * i + 0] = make_uint4(pack2(nxh, nxl), pack2(nxh, nyh),
                                  pack2(nyl, nyh), pack2(nzh, nzl));
    fragB[2 * i + 1] = make_uint4(pack2(nzh, one), pack2(one, hh),
                                  pack2(hl, 0), 0u);
    tmins[i] = 0x7f7f7f7fu;     // ~3.39e38 (flushed values are clamped >= 0)
    if (i < BATCH) out[i] = 0.0f;
}

__global__ __launch_bounds__(BLOCK) void chamfer_nn(
    const float* __restrict__ src, const uint4* __restrict__ fragB,
    float* __restrict__ ws1, unsigned int* __restrict__ tmins)
{
    __shared__ uint4 Bfr0[CH], Bfr1[CH];   // staged B frags (k-half 0 / 1)
    __shared__ int   sht[CH];              // per-db-point col-min (float bits)

    const int tid  = threadIdx.x;
    const int lane = tid & 63;
    const int w    = tid >> 6;
    const int half = lane >> 5;
    const int l31  = lane & 31;
    const int qb   = blockIdx.x;
    const int b    = blockIdx.y;
    const int ds   = blockIdx.z;

    // ---- build two A-fragments (queries w*64+l31 and +32) ----
    const unsigned short one = bf16h(1.0f);
    bf16x8 af0, af1;
#pragma unroll
    for (int g = 0; g < 2; g++) {
        const int q = qb * QTILE + w * 64 + g * 32 + l31;
        const float* qp = src + ((size_t)b * NPTS + q) * 3;
        float qx = qp[0], qy = qp[1], qz = qp[2];
        float hq = 0.5f * fmaf(qx, qx, fmaf(qy, qy, qz * qz));
        unsigned short xh = bf16h(qx), xl = bf16h(qx - bf16tof(xh));
        unsigned short yh = bf16h(qy), yl = bf16h(qy - bf16tof(yh));
        unsigned short zh = bf16h(qz), zl = bf16h(qz - bf16tof(zh));
        unsigned short qh = bf16h(hq), ql = bf16h(hq - bf16tof(qh));
        bf16x8 a;
        if (half == 0) {
            a[0] = (short)xh; a[1] = (short)xh; a[2] = (short)xl;
            a[3] = (short)yh; a[4] = (short)yh; a[5] = (short)yl;
            a[6] = (short)zh; a[7] = (short)zh;
        } else {
            a[0] = (short)zl; a[1] = (short)qh; a[2] = (short)ql;
            a[3] = (short)one; a[4] = (short)one;
            a[5] = 0; a[6] = 0; a[7] = 0;
        }
        if (g == 0) af0 = a; else af1 = a;
    }

    float rmn0[16], rmn1[16];
#pragma unroll
    for (int r = 0; r < 16; r++) { rmn0[r] = 3.4e38f; rmn1[r] = 3.4e38f; }
    const f32x16 zz = {};
    const uint4* Bh = half ? Bfr1 : Bfr0;

    const uint4* fb = fragB + ((size_t)b * NPTS + (size_t)ds * DBR) * 2;
    unsigned int* tm = tmins + (size_t)b * NPTS + (size_t)ds * DBR;

    // reg-stage chunk 0 (T14 pattern: load early, write after barrier)
    uint4 r0 = fb[2 * tid + 0], r1 = fb[2 * tid + 1];

    for (int c = 0; c < NCH; ++c) {
        __syncthreads();                     // prev chunk's reads/ds_min done
        if (c > 0) {                         // flush prev col-mins (clamped)
            float v = fmaxf(__int_as_float(sht[tid]), 0.0f);
            atomicMin(&tm[(c - 1) * CH + tid], __float_as_uint(v));
        }
        Bfr0[tid] = r0;
        Bfr1[tid] = r1;
        sht[tid] = 0x7f7f7f7f;
        __syncthreads();                     // staging + init visible
        if (c + 1 < NCH) {                   // prefetch next chunk into regs
            r0 = fb[2 * (((c + 1) * CH) + tid) + 0];
            r1 = fb[2 * (((c + 1) * CH) + tid) + 1];
        }

#pragma unroll
        for (int tp = 0; tp < CH / 64; ++tp) {   // 4 tile-pairs
            const int t0 = tp * 2, t1 = tp * 2 + 1;
            bf16x8 b0 = *reinterpret_cast<const bf16x8*>(&Bh[t0 * 32 + l31]);
            bf16x8 b1 = *reinterpret_cast<const bf16x8*>(&Bh[t1 * 32 + l31]);
            f32x16 a00 = __builtin_amdgcn_mfma_f32_32x32x16_bf16(af0, b0, zz, 0, 0, 0);
            f32x16 a01 = __builtin_amdgcn_mfma_f32_32x32x16_bf16(af0, b1, zz, 0, 0, 0);
            f32x16 a10 = __builtin_amdgcn_mfma_f32_32x32x16_bf16(af1, b0, zz, 0, 0, 0);
            f32x16 a11 = __builtin_amdgcn_mfma_f32_32x32x16_bf16(af1, b1, zz, 0, 0, 0);
#pragma unroll
            for (int r = 0; r < 16; r++) {
                rmn0[r] = fmin3(rmn0[r], a00[r], a01[r]);   // s2t: min over db
                rmn1[r] = fmin3(rmn1[r], a10[r], a11[r]);
            }
            // t2s: min over this block's 64 queries (both A-frags)
            float c0 = fminf(tree16(a00), tree16(a10));
            float c1 = fminf(tree16(a01), tree16(a11));
            atomicMin(&sht[t0 * 32 + l31], __float_as_int(c0));  // 2-way: free
            atomicMin(&sht[t1 * 32 + l31], __float_as_int(c1));
        }
    }
    __syncthreads();
    {
        float v = fmaxf(__int_as_float(sht[tid]), 0.0f);
        atomicMin(&tm[(NCH - 1) * CH + tid], __float_as_uint(v));
    }

    // ---- s2t tail: fold cols 32->8 via 2 shfl_xor, store 8 partials/query
    // (replaces R5's 32-way same-address LDS atomic serialization) ----
    float* w1 = ws1 + ((size_t)ds * BATCH + b) * NPTS * 8;
    const int qbase = qb * QTILE + w * 64;
#pragma unroll
    for (int r = 0; r < 16; r++) {
        float a = rmn0[r], bv = rmn1[r];
        a  = fminf(a,  __shfl_xor(a,  16, 64));
        bv = fminf(bv, __shfl_xor(bv, 16, 64));
        a  = fminf(a,  __shfl_xor(a,  8, 64));
        bv = fminf(bv, __shfl_xor(bv, 8, 64));
        if (l31 < 8) {
            const int row = (r & 3) + 8 * (r >> 2) + 4 * half;
            w1[(size_t)(qbase + row) * 8 + l31]      = a;
            w1[(size_t)(qbase + 32 + row) * 8 + l31] = bv;
        }
    }
}

// ---- final: reduce ws1 (s2t) + tmins (t2s), sum, atomicAdd out ----
__global__ __launch_bounds__(BLOCK) void chamfer_final(
    const float* __restrict__ ws1, const unsigned int* __restrict__ tmins,
    float* __restrict__ out)
{
    const int seg = blockIdx.x;   // 0..15 = s2t segments, 16 = t2s
    const int b   = blockIdx.y;
    const int tid = threadIdx.x;
    float acc = 0.0f;

    if (seg < 16) {
#pragma unroll
        for (int rep = 0; rep < 2; rep++) {
            const int q = seg * 512 + rep * 256 + tid;
            float m = 3.4e38f;
#pragma unroll
            for (int d = 0; d < DSPLIT; d++) {
                const float4* p = (const float4*)(ws1 +
                    ((size_t)d * BATCH + b) * NPTS * 8 + (size_t)q * 8);
                float4 v0 = p[0], v1 = p[1];
                m = fmin3(m, v0.x, v0.y); m = fmin3(m, v0.z, v0.w);
                m = fmin3(m, v1.x, v1.y); m = fmin3(m, v1.z, v1.w);
            }
            acc += fmaxf(m, 0.0f);
        }
    } else {
#pragma unroll 8
        for (int k = 0; k < NPTS / BLOCK; k++)
            acc += __uint_as_float(tmins[(size_t)b * NPTS + k * BLOCK + tid]);
    }

    for (int off = 32; off > 0; off >>= 1) acc += __shfl_down(acc, off, 64);
    __shared__ float wsum[4];
    if ((tid & 63) == 0) wsum[tid >> 6] = acc;
    __syncthreads();
    if (tid == 0)   // stored values are half-distances: d = 2h
        atomicAdd(&out[b],
                  (wsum[0] + wsum[1] + wsum[2] + wsum[3]) * (2.0f / (float)NPTS));
}

extern "C" void kernel_launch(void* const* d_in, const int* in_sizes, int n_in,
                              void* d_out, int out_size, void* d_ws, size_t ws_size,
                              hipStream_t stream) {
    const float* src = (const float*)d_in[0];  // [B, N, 3]
    const float* tgt = (const float*)d_in[1];  // [B, M, 3]
    float* out = (float*)d_out;                // [B]

    uint4* fragB        = (uint4*)d_ws;                   // 2 MB
    float* ws1          = (float*)(fragB + FRAGB_N);      // 4 MB
    unsigned int* tmins = (unsigned int*)(ws1 + WS1_N);   // 256 KB

    chamfer_prep<<<BATCH * NPTS / BLOCK, BLOCK, 0, stream>>>(tgt, fragB, tmins, out);
    chamfer_nn<<<dim3(QB, BATCH, DSPLIT), BLOCK, 0, stream>>>(src, fragB, ws1, tmins);
    chamfer_final<<<dim3(17, BATCH), BLOCK, 0, stream>>>(ws1, tmins, out);
}

// Round 7
// 106.154 us; speedup vs baseline: 1.1875x; 1.0049x over previous
//
#include <hip/hip_runtime.h>

// Chamfer via MFMA half-distance matrix, v3.
// R6 post-mortem: nn 48.8us, MfmaUtil 12.8, Occupancy 17% -- DSPLIT=2 gave
// only 512 blocks = 2 waves/SIMD; MFMA->min-tree dependency chains exposed.
// Also: per-chunk global atomicMin flush sat between barriers (syncthreads
// drains vmcnt -> ~900cyc atomic round trip x16 chunks), and ws1 cost
// 4MB stores + 4MB final reads.
// R7: (1) DSPLIT=4 -> 1024 blocks = 4 waves/SIMD; (2) per-chunk col-mins in
// LDS sht[NCH][CH], ONE global flush after the K-loop (no global ops between
// in-loop barriers); (3) s2t folded fully in-wave (5 shfl_xor) + global
// atomicMin into smins (256KB) -- ws1 eliminated; final reads 512KB.
//
// Math (R5/R6-verified, absmax 0.0): h = 0.5|q|^2 + 0.5|t|^2 - q.t = d/2
// via K=16 of v_mfma_f32_32x32x16_bf16 with bf16 hi/lo split:
//   A(q): half0 [xh xh xl yh yh yl zh zh]  half1 [zl qh ql 1 1 0 0 0]
//   B(t): half0 [nxh nxl nxh nyh nyl nyh nzh nzl] half1 [nzh 1 1 hh hl 0 0 0]
// C layout (m74/m101): col=lane&31, row=(reg&3)+8*(reg>>2)+4*(lane>>5).

typedef float f32x16 __attribute__((ext_vector_type(16)));
typedef short bf16x8 __attribute__((ext_vector_type(8)));

constexpr int BATCH  = 8;
constexpr int NPTS   = 8192;
constexpr int BLOCK  = 256;            // 4 waves
constexpr int QTILE  = 256;            // queries per block (64 per wave)
constexpr int QB     = NPTS / QTILE;   // 32 query blocks
constexpr int DSPLIT = 4;
constexpr int DBR    = NPTS / DSPLIT;  // 2048 db points per block
constexpr int CH     = 256;            // db points per LDS chunk
constexpr int NCH    = DBR / CH;       // 8 chunks

// workspace: fragB [B][NPTS][2] uint4 (2MB) | smins [B][NPTS] u32 (256KB)
//            | tmins [B][NPTS] u32 (256KB)
constexpr size_t FRAGB_N = (size_t)BATCH * NPTS * 2;
constexpr size_t SM_N    = (size_t)BATCH * NPTS;

static __device__ __forceinline__ float fmin3(float a, float b, float c) {
    return fminf(fminf(a, b), c);   // v_min3_f32
}
static __device__ __forceinline__ unsigned short bf16h(float f) {
    unsigned int u = __float_as_uint(f);
    u += 0x7fffu + ((u >> 16) & 1u);           // RNE
    return (unsigned short)(u >> 16);
}
static __device__ __forceinline__ float bf16tof(unsigned short h) {
    return __uint_as_float(((unsigned int)h) << 16);
}
static __device__ __forceinline__ unsigned int pack2(unsigned short a, unsigned short b) {
    return (unsigned int)a | ((unsigned int)b << 16);
}
static __device__ __forceinline__ float tree16(const f32x16& a) {
    float m = fmin3(a[0], a[1], a[2]);
    m = fmin3(m, a[3], a[4]);   m = fmin3(m, a[5], a[6]);
    m = fmin3(m, a[7], a[8]);   m = fmin3(m, a[9], a[10]);
    m = fmin3(m, a[11], a[12]); m = fmin3(m, a[13], a[14]);
    return fminf(m, a[15]);
}

// ---- prep: tgt -> split-bf16 B-fragments; init smins/tmins; zero out ----
__global__ __launch_bounds__(BLOCK) void chamfer_prep(
    const float* __restrict__ tgt, uint4* __restrict__ fragB,
    unsigned int* __restrict__ smins, unsigned int* __restrict__ tmins,
    float* __restrict__ out)
{
    const int i = blockIdx.x * BLOCK + threadIdx.x;   // [0, B*NPTS)
    const float* tp = tgt + (size_t)i * 3;
    float px = tp[0], py = tp[1], pz = tp[2];
    float nx = -px, ny = -py, nz = -pz;
    float ht = 0.5f * fmaf(px, px, fmaf(py, py, pz * pz));
    const unsigned short one = bf16h(1.0f);
    unsigned short nxh = bf16h(nx), nxl = bf16h(nx - bf16tof(nxh));
    unsigned short nyh = bf16h(ny), nyl = bf16h(ny - bf16tof(nyh));
    unsigned short nzh = bf16h(nz), nzl = bf16h(nz - bf16tof(nzh));
    unsigned short hh = bf16h(ht),  hl = bf16h(ht - bf16tof(hh));
    fragB[2 * i + 0] = make_uint4(pack2(nxh, nxl), pack2(nxh, nyh),
                                  pack2(nyl, nyh), pack2(nzh, nzl));
    fragB[2 * i + 1] = make_uint4(pack2(nzh, one), pack2(one, hh),
                                  pack2(hl, 0), 0u);
    smins[i] = 0x7f7f7f7fu;
    tmins[i] = 0x7f7f7f7fu;
    if (i < BATCH) out[i] = 0.0f;
}

__global__ __launch_bounds__(BLOCK) void chamfer_nn(
    const float* __restrict__ src, const uint4* __restrict__ fragB,
    unsigned int* __restrict__ smins, unsigned int* __restrict__ tmins)
{
    __shared__ uint4 Bfr0[CH], Bfr1[CH];   // staged B frags (k-half 0 / 1)
    __shared__ int   sht[NCH][CH];         // per-chunk col-mins (float bits)

    const int tid  = threadIdx.x;
    const int lane = tid & 63;
    const int w    = tid >> 6;
    const int half = lane >> 5;
    const int l31  = lane & 31;
    const int qb   = blockIdx.x;
    const int b    = blockIdx.y;
    const int ds   = blockIdx.z;

    // init all per-chunk col-min arrays once (no in-loop re-init)
#pragma unroll
    for (int c = 0; c < NCH; c++) sht[c][tid] = 0x7f7f7f7f;

    // ---- build two A-fragments (queries w*64+l31 and +32) ----
    const unsigned short one = bf16h(1.0f);
    bf16x8 af0, af1;
#pragma unroll
    for (int g = 0; g < 2; g++) {
        const int q = qb * QTILE + w * 64 + g * 32 + l31;
        const float* qp = src + ((size_t)b * NPTS + q) * 3;
        float qx = qp[0], qy = qp[1], qz = qp[2];
        float hq = 0.5f * fmaf(qx, qx, fmaf(qy, qy, qz * qz));
        unsigned short xh = bf16h(qx), xl = bf16h(qx - bf16tof(xh));
        unsigned short yh = bf16h(qy), yl = bf16h(qy - bf16tof(yh));
        unsigned short zh = bf16h(qz), zl = bf16h(qz - bf16tof(zh));
        unsigned short qh = bf16h(hq), ql = bf16h(hq - bf16tof(qh));
        bf16x8 a;
        if (half == 0) {
            a[0] = (short)xh; a[1] = (short)xh; a[2] = (short)xl;
            a[3] = (short)yh; a[4] = (short)yh; a[5] = (short)yl;
            a[6] = (short)zh; a[7] = (short)zh;
        } else {
            a[0] = (short)zl; a[1] = (short)qh; a[2] = (short)ql;
            a[3] = (short)one; a[4] = (short)one;
            a[5] = 0; a[6] = 0; a[7] = 0;
        }
        if (g == 0) af0 = a; else af1 = a;
    }

    float rmn0[16], rmn1[16];
#pragma unroll
    for (int r = 0; r < 16; r++) { rmn0[r] = 3.4e38f; rmn1[r] = 3.4e38f; }
    const f32x16 zz = {};
    const uint4* Bh = half ? Bfr1 : Bfr0;

    const uint4* fb = fragB + ((size_t)b * NPTS + (size_t)ds * DBR) * 2;

    // reg-stage chunk 0 (T14: issue early, write after barrier)
    uint4 r0 = fb[2 * tid + 0], r1 = fb[2 * tid + 1];

    for (int c = 0; c < NCH; ++c) {
        __syncthreads();                     // prev chunk's LDS reads done
        Bfr0[tid] = r0;
        Bfr1[tid] = r1;
        __syncthreads();                     // staging visible
        if (c + 1 < NCH) {                   // prefetch next chunk into regs
            r0 = fb[2 * ((c + 1) * CH + tid) + 0];
            r1 = fb[2 * ((c + 1) * CH + tid) + 1];
        }

#pragma unroll
        for (int tp = 0; tp < CH / 64; ++tp) {   // 4 tile-pairs
            const int t0 = tp * 2, t1 = tp * 2 + 1;
            bf16x8 b0 = *reinterpret_cast<const bf16x8*>(&Bh[t0 * 32 + l31]);
            bf16x8 b1 = *reinterpret_cast<const bf16x8*>(&Bh[t1 * 32 + l31]);
            f32x16 a00 = __builtin_amdgcn_mfma_f32_32x32x16_bf16(af0, b0, zz, 0, 0, 0);
            f32x16 a01 = __builtin_amdgcn_mfma_f32_32x32x16_bf16(af0, b1, zz, 0, 0, 0);
            f32x16 a10 = __builtin_amdgcn_mfma_f32_32x32x16_bf16(af1, b0, zz, 0, 0, 0);
            f32x16 a11 = __builtin_amdgcn_mfma_f32_32x32x16_bf16(af1, b1, zz, 0, 0, 0);
#pragma unroll
            for (int r = 0; r < 16; r++) {
                rmn0[r] = fmin3(rmn0[r], a00[r], a01[r]);   // s2t: min over db
                rmn1[r] = fmin3(rmn1[r], a10[r], a11[r]);
            }
            // t2s: min over this wave's 64 queries; 2-way same-addr (free)
            float c0 = fminf(tree16(a00), tree16(a10));
            float c1 = fminf(tree16(a01), tree16(a11));
            atomicMin(&sht[c][t0 * 32 + l31], __float_as_int(c0));
            atomicMin(&sht[c][t1 * 32 + l31], __float_as_int(c1));
        }
    }
    __syncthreads();   // all waves' LDS atomics complete

    // ---- t2s flush: one global atomic pass, AFTER the K-loop ----
    unsigned int* tm = tmins + (size_t)b * NPTS + (size_t)ds * DBR;
#pragma unroll
    for (int c = 0; c < NCH; c++) {
        float v = fmaxf(__int_as_float(sht[c][tid]), 0.0f);
        atomicMin(&tm[c * CH + tid], __float_as_uint(v));
    }

    // ---- s2t: full in-wave fold (cols 32->1) + global atomicMin ----
    unsigned int* sm = smins + (size_t)b * NPTS;
    const int qbase = qb * QTILE + w * 64;
#pragma unroll
    for (int r = 0; r < 16; r++) {
        float a = rmn0[r], bv = rmn1[r];
#pragma unroll
        for (int off = 16; off > 0; off >>= 1) {
            a  = fminf(a,  __shfl_xor(a,  off, 64));
            bv = fminf(bv, __shfl_xor(bv, off, 64));
        }
        if (l31 == 0) {   // lanes 0 (half0 rows) and 32 (half1 rows)
            const int row = (r & 3) + 8 * (r >> 2) + 4 * half;
            atomicMin(&sm[qbase + row],      __float_as_uint(fmaxf(a,  0.0f)));
            atomicMin(&sm[qbase + 32 + row], __float_as_uint(fmaxf(bv, 0.0f)));
        }
    }
}

// ---- final: sum smins + tmins (512KB total), atomicAdd into out ----
__global__ __launch_bounds__(BLOCK) void chamfer_final(
    const unsigned int* __restrict__ smins, const unsigned int* __restrict__ tmins,
    float* __restrict__ out)
{
    const int seg = blockIdx.x;   // 4 segments of 2048 per array
    const int b   = blockIdx.y;
    const int tid = threadIdx.x;
    float acc = 0.0f;
#pragma unroll
    for (int k = 0; k < 8; k++) {
        const size_t i = (size_t)b * NPTS + seg * 2048 + k * BLOCK + tid;
        acc += __uint_as_float(smins[i]) + __uint_as_float(tmins[i]);
    }
    for (int off = 32; off > 0; off >>= 1) acc += __shfl_down(acc, off, 64);
    __shared__ float wsum[4];
    if ((tid & 63) == 0) wsum[tid >> 6] = acc;
    __syncthreads();
    if (tid == 0)   // stored values are half-distances: d = 2h
        atomicAdd(&out[b],
                  (wsum[0] + wsum[1] + wsum[2] + wsum[3]) * (2.0f / (float)NPTS));
}

extern "C" void kernel_launch(void* const* d_in, const int* in_sizes, int n_in,
                              void* d_out, int out_size, void* d_ws, size_t ws_size,
                              hipStream_t stream) {
    const float* src = (const float*)d_in[0];  // [B, N, 3]
    const float* tgt = (const float*)d_in[1];  // [B, M, 3]
    float* out = (float*)d_out;                // [B]

    uint4* fragB        = (uint4*)d_ws;                    // 2 MB
    unsigned int* smins = (unsigned int*)(fragB + FRAGB_N);// 256 KB
    unsigned int* tmins = smins + SM_N;                    // 256 KB

    chamfer_prep<<<BATCH * NPTS / BLOCK, BLOCK, 0, stream>>>(tgt, fragB, smins, tmins, out);
    chamfer_nn<<<dim3(QB, BATCH, DSPLIT), BLOCK, 0, stream>>>(src, fragB, smins, tmins);
    chamfer_final<<<dim3(4, BATCH), BLOCK, 0, stream>>>(smins, tmins, out);
}